// Round 4
// baseline (291.864 us; speedup 1.0000x reference)
//
#include <hip/hip_runtime.h>
#include <cstdint>
#include <cstddef>

// ---------------------------------------------------------------------------
// MSA: out = proj(softmax(Q K^T * scale) V) for B=4, N=2048, C=1024, H=16, HD=64
// bf16/f16 MFMA pipeline:
//   1. convert x -> bf16                       [8192,1024]
//   2. transpose-convert w_qkv -> bf16 [3072,1024], w_proj -> bf16 [1024,1024]
//   3. GEMM qkv: 256x128 tile, BK=64, 8 waves, TRIPLE-buffered LDS,
//      counted s_waitcnt vmcnt(6), 2 phases/K-tile, setprio(1) around MFMA.
//      XCD/L2-aware block remap: XCD c owns m-panels [4c,4c+4); n in chunks
//      of 8 -> resident set A 2MB + B 2MB = one 4MB L2.
//   4. attention: 128 q/block, 4 waves x 32 q-rows (256 thr), BKV=64,
//      S^T=K·Q^T, no-max softmax, p=exp2(s). PV now uses K=32 f16 MFMA:
//      P A-frags (k=quad*8+j) built from S^T's C-layout (kv=quad*4+r) by a
//      quad-exchange: dst(quad t, word w) <- src(quad 2(t&1)+(w>>1), word w&1,
//      kvt parity t>>1) via 8 ds_bpermute + 4 cndmask per frag (2 constant
//      addresses). Halves PV MFMA issue count (matrix pipe was ~50/95 us).
//      K+V LDS double-buffered, barrier-first prefetch, 1 barrier/tile,
//      4 blocks/CU. Bijective XCD swizzle (measured: FETCH 142->28 MB).
//   5. GEMM proj (same pipelined kernel, MODE 1) + bias -> fp32 d_out
// ---------------------------------------------------------------------------

typedef __attribute__((ext_vector_type(8))) short short8;   // 8 x bf16 (4 VGPRs)
typedef __attribute__((ext_vector_type(4))) float f32x4;    // MFMA C/D
typedef _Float16 half4 __attribute__((ext_vector_type(4))); // 16x16x16 A/B frag
typedef _Float16 half8 __attribute__((ext_vector_type(8))); // 16x16x32 A/B frag

#if __has_builtin(__builtin_amdgcn_exp2f)
#define EXP2F(x) __builtin_amdgcn_exp2f(x)
#else
#define EXP2F(x) __expf((x) * 0.69314718056f)
#endif

__device__ __forceinline__ short f2bf(float x) {            // RNE float->bf16 bits
  unsigned u = __builtin_bit_cast(unsigned, x);
  u += 0x7fffu + ((u >> 16) & 1u);
  return (short)(u >> 16);
}

__device__ __forceinline__ unsigned pkh(float a, float b) { // pack 2xf32 -> f16x2
  auto h = __builtin_amdgcn_cvt_pkrtz(a, b);                // __fp16 ext_vector(2)
  return __builtin_bit_cast(unsigned, h);
}

__device__ __forceinline__ void async16(const void* g, void* l) {
  // 16B per lane, LDS dest = wave-uniform base + lane*16
  __builtin_amdgcn_global_load_lds(
      (const __attribute__((address_space(1))) unsigned*)g,
      (__attribute__((address_space(3))) unsigned*)l, 16, 0, 0);
}

// ------------------------------- casts -------------------------------------

__global__ __launch_bounds__(256) void convert_kernel(const float* __restrict__ in,
                                                      short* __restrict__ out) {
  int i = blockIdx.x * 256 + threadIdx.x;          // 8 elems/thread
  const float4* p = (const float4*)in + (size_t)i * 2;
  float4 a = p[0], b = p[1];
  short8 r;
  r[0] = f2bf(a.x); r[1] = f2bf(a.y); r[2] = f2bf(a.z); r[3] = f2bf(a.w);
  r[4] = f2bf(b.x); r[5] = f2bf(b.y); r[6] = f2bf(b.z); r[7] = f2bf(b.w);
  *((short8*)out + i) = r;
}

// in: fp32 [K,N] row-major  ->  out: bf16 [N,K] row-major
__global__ __launch_bounds__(256) void wtrans_kernel(const float* __restrict__ in,
                                                     short* __restrict__ out,
                                                     int K, int N) {
  __shared__ float tile[32][33];
  int n0 = blockIdx.x * 32, k0 = blockIdx.y * 32;
  int tx = threadIdx.x, ty = threadIdx.y;          // block (32,8)
  for (int r = ty; r < 32; r += 8)
    tile[r][tx] = in[(size_t)(k0 + r) * N + n0 + tx];
  __syncthreads();
  for (int r = ty; r < 32; r += 8)
    out[(size_t)(n0 + r) * K + k0 + tx] = f2bf(tile[tx][r]);
}

// ------------------------------- GEMM --------------------------------------
// C[M,Nn] = A[M,1024] * Bt[Nn,1024]^T ; 256x128 block tile, BK=64, 8 waves
// (4M x 2N, 64x64 each = 4x4 of 16x16x32 MFMA). Triple-buffered LDS: while
// computing K-tile t, stage t+2; per-tile wait is vmcnt(6) (= the 6 stage
// loads just issued), so t+1's loads (a full K-tile old) are retired and
// NOTHING is drained at barriers (raw s_barrier, no __syncthreads).
// Block remap (assumes round-robin id->XCD, id%8): XCD c gets m-panels
// [c*MC, (c+1)*MC), n iterated in chunks of 8 -> L2-resident A+B panels.
// MODE 0: QKV epilogue (bias, scale Q by SCALE*log2e, scatter q/k bf16, vT f16)
// MODE 1: proj epilogue (bias, fp32 out)

template <int MODE>
__global__ __launch_bounds__(512, 2) void gemm_kernel(
    const short* __restrict__ A, const short* __restrict__ Bt,
    const float* __restrict__ bias, int Nn,
    short* __restrict__ qb, short* __restrict__ kb, short* __restrict__ vtb,
    float* __restrict__ outp) {
  constexpr int K = 1024;
  constexpr int NT = K / 64;                       // 16 K-tiles
  __shared__ __align__(16) short As[3][256 * 64];  // 3 x 32 KB
  __shared__ __align__(16) short Bs[3][128 * 64];  // 3 x 16 KB   (144 KB total)
  const int tid = threadIdx.x, wave = tid >> 6, lane = tid & 63;
  const int quad = lane >> 4, l16 = lane & 15;

  // XCD/L2-aware remap: id -> (c = id%8, j = id/8); XCD c owns MC m-panels;
  // within, n in chunks of 8 (requires gridDim.x % 8 == 0, gridDim.y % 8 == 0).
  const unsigned bid = blockIdx.x + gridDim.x * blockIdx.y;
  const unsigned c = bid & 7u, j = bid >> 3;
  const unsigned MC = gridDim.y >> 3;              // m-panels per XCD
  const unsigned chunk = MC * 8u;                  // blocks per n-chunk per XCD
  const unsigned nc = j / chunk, rem = j - nc * chunk;
  const unsigned m_idx = c * MC + (rem >> 3);
  const unsigned n_idx = nc * 8u + (rem & 7u);
  const int m0 = (int)m_idx * 256, n0 = (int)n_idx * 128;

  const int wrow = (wave >> 1) * 64, wcol = (wave & 1) * 64;

  // staging: row = i*64 + (tid>>3), chunk(16B) = tid&7, src chunk XOR (row&7)
  const int srow = tid >> 3;
  const int schunk = ((tid & 7) ^ (srow & 7)) * 8;          // shorts
  const short* Ag = A + (size_t)(m0 + srow) * K + schunk;
  const short* Bg = Bt + (size_t)(n0 + srow) * K + schunk;
  const int fsw = l16 & 7;

  f32x4 acc[4][4] = {};
  short8 af[4][2], bf[2][2];

  auto stageA = [&](int b, int kt) {
#pragma unroll
    for (int i = 0; i < 4; ++i)
      async16(Ag + (size_t)(i * 64) * K + kt * 64,
              (char*)As[b] + i * 8192 + tid * 16);
  };
  auto stageB = [&](int b, int kt) {
#pragma unroll
    for (int i = 0; i < 2; ++i)
      async16(Bg + (size_t)(i * 64) * K + kt * 64,
              (char*)Bs[b] + i * 8192 + tid * 16);
  };

  // prologue: stage K-tiles 0 and 1; wait for 0, keep 1 in flight
  stageA(0, 0); stageB(0, 0);
  stageA(1, 1); stageB(1, 1);
  asm volatile("s_waitcnt vmcnt(6)" ::: "memory");
  __builtin_amdgcn_s_barrier();

  int cb = 0;
  for (int t = 0; t < NT; ++t) {
    int sb = cb + 2; if (sb >= 3) sb -= 3;
    const short* Ab = As[cb];
    const short* Bb = Bs[cb];

    // ---- phase 0: all 8 A-frags + B-frags n0,n1; stage A(t+2) ----
#pragma unroll
    for (int mf = 0; mf < 4; ++mf)
#pragma unroll
      for (int ks = 0; ks < 2; ++ks)
        af[mf][ks] = *(const short8*)
            &Ab[(wrow + mf * 16 + l16) * 64 + (((ks * 4 + quad) ^ fsw) << 3)];
#pragma unroll
    for (int j2 = 0; j2 < 2; ++j2)
#pragma unroll
      for (int ks = 0; ks < 2; ++ks)
        bf[j2][ks] = *(const short8*)
            &Bb[(wcol + j2 * 16 + l16) * 64 + (((ks * 4 + quad) ^ fsw) << 3)];
    if (t + 2 < NT) stageA(sb, t + 2);
    __builtin_amdgcn_s_barrier();
    __builtin_amdgcn_s_setprio(1);
#pragma unroll
    for (int ks = 0; ks < 2; ++ks)
#pragma unroll
      for (int mf = 0; mf < 4; ++mf)
#pragma unroll
        for (int j2 = 0; j2 < 2; ++j2)
          acc[mf][j2] = __builtin_amdgcn_mfma_f32_16x16x32_bf16(
              af[mf][ks], bf[j2][ks], acc[mf][j2], 0, 0, 0);
    __builtin_amdgcn_s_setprio(0);
    __builtin_amdgcn_s_barrier();

    // ---- phase 1: B-frags n2,n3 (A reused from regs); stage B(t+2) ----
#pragma unroll
    for (int j2 = 0; j2 < 2; ++j2)
#pragma unroll
      for (int ks = 0; ks < 2; ++ks)
        bf[j2][ks] = *(const short8*)
            &Bb[(wcol + (2 + j2) * 16 + l16) * 64 + (((ks * 4 + quad) ^ fsw) << 3)];
    if (t + 2 < NT) stageB(sb, t + 2);
    __builtin_amdgcn_s_barrier();
    __builtin_amdgcn_s_setprio(1);
#pragma unroll
    for (int ks = 0; ks < 2; ++ks)
#pragma unroll
      for (int mf = 0; mf < 4; ++mf)
#pragma unroll
        for (int j2 = 0; j2 < 2; ++j2)
          acc[mf][2 + j2] = __builtin_amdgcn_mfma_f32_16x16x32_bf16(
              af[mf][ks], bf[j2][ks], acc[mf][2 + j2], 0, 0, 0);
    __builtin_amdgcn_s_setprio(0);
    // counted wait: t+2's 6 loads stay in flight; everything older retired.
    if (t < NT - 2)
      asm volatile("s_waitcnt vmcnt(6)" ::: "memory");
    else if (t == NT - 2)
      asm volatile("s_waitcnt vmcnt(0)" ::: "memory");   // last tile's loads
    __builtin_amdgcn_s_barrier();
    cb = cb + 1; if (cb >= 3) cb -= 3;
  }

  // epilogue: C/D layout col = l16, row = quad*4 + reg
  if (MODE == 0) {
#pragma unroll
    for (int mf = 0; mf < 4; ++mf) {
      int row0 = m0 + wrow + mf * 16 + quad * 4;
      int b = row0 >> 11, n = row0 & 2047;
#pragma unroll
      for (int nf = 0; nf < 4; ++nf) {
        int col = n0 + wcol + nf * 16 + l16;
        float bv = bias[col];
        float v0 = acc[mf][nf][0] + bv, v1 = acc[mf][nf][1] + bv;
        float v2 = acc[mf][nf][2] + bv, v3 = acc[mf][nf][3] + bv;
        int which = col >> 10;
        int h = (col >> 6) & 15;
        int d = col & 63;
        size_t bh = (size_t)(b * 16 + h);
        if (which == 0) {             // Q, pre-scaled by SCALE*log2(e)
          const float qs = 0.18033688f;   // 0.125 * 1.44269504
          size_t base = (bh * 2048 + n) * 64 + d;
          qb[base]       = f2bf(v0 * qs);
          qb[base + 64]  = f2bf(v1 * qs);
          qb[base + 128] = f2bf(v2 * qs);
          qb[base + 192] = f2bf(v3 * qs);
        } else if (which == 1) {      // K
          size_t base = (bh * 2048 + n) * 64 + d;
          kb[base]       = f2bf(v0);
          kb[base + 64]  = f2bf(v1);
          kb[base + 128] = f2bf(v2);
          kb[base + 192] = f2bf(v3);
        } else {                      // V transposed: [bh, d, n] f16, 4 tokens
          uint2 pk;
          pk.x = pkh(v0, v1);
          pk.y = pkh(v2, v3);
          *(uint2*)&vtb[(bh * 64 + d) * 2048 + n] = pk;
        }
      }
    }
  } else {
#pragma unroll
    for (int mf = 0; mf < 4; ++mf) {
      int row0 = m0 + wrow + mf * 16 + quad * 4;
#pragma unroll
      for (int nf = 0; nf < 4; ++nf) {
        int col = n0 + wcol + nf * 16 + l16;
        float bv = bias[col];
        outp[(size_t)row0 * Nn + col]       = acc[mf][nf][0] + bv;
        outp[(size_t)(row0 + 1) * Nn + col] = acc[mf][nf][1] + bv;
        outp[(size_t)(row0 + 2) * Nn + col] = acc[mf][nf][2] + bv;
        outp[(size_t)(row0 + 3) * Nn + col] = acc[mf][nf][3] + bv;
      }
    }
  }
}

// ----------------------------- attention -----------------------------------
// One block = one (b,h) x 128 q-rows; 4 waves, 32 q-rows each. BKV = 64.
// Q pre-scaled by SCALE*log2e. qb/kb: [BH,2048,64] bf16; vtb: [BH,64,2048] f16.
// S^T = K Q^T via 16x16x32 bf16 (A=K m=kv, B=Q n=q): lane holds
// q=qt*16+l16, kv=(2*blk+vv)*16 + quad*4 + r.
// PV uses 16x16x32 f16 (A=P m=q k=kv 32-wide, B=V n=d): A-frag needs
// k=quad*8+j. Quad-exchange of packed f16 pairs: solving
// v*16 + s*4 + 2u = t*8 + 2w gives dst(quad t, word w) <- src lane
// s = 2*(t&1)+(w>>1) (same l16), src word u = w&1, kvt parity v&1 = t>>1.
// -> per frag: 8 ds_bpermute (2 const addrs) + 4 cndmask(lane>=32).
// K+V double-buffered, barrier-first prefetch, 1 barrier/tile, 4 blocks/CU.
// Bijective XCD swizzle: XCD c covers bh in [8c,8c+8) -> K/V set 4MB = L2.
// ob: [B, 2048, 1024] bf16 attention output.

__global__ __launch_bounds__(256, 4) void attn_kernel(
    const short* __restrict__ qb, const short* __restrict__ kb,
    const short* __restrict__ vtb, short* __restrict__ ob) {
  __shared__ __align__(16) short Ks[2][64 * 64];  // bf16 [kv][d]
  __shared__ __align__(16) short Vs[2][64 * 64];  // f16  [d][kv]
  __shared__ __align__(16) float Ls[4][32];
  const int tid = threadIdx.x, wave = tid >> 6, lane = tid & 63;
  const int quad = lane >> 4, l16 = lane & 15;
  // XCD-bijective remap: linear id n -> n' = (n%8)*128 + n/8, so XCD c
  // (blocks n with n%8==c under round-robin dispatch) covers bh in [8c,8c+8).
  int nlin = blockIdx.x + blockIdx.y * 16;
  nlin = (nlin & 7) * 128 + (nlin >> 3);
  const int q0 = (nlin & 15) * 128;
  const int bh = nlin >> 4;
  const short* Qg = qb + (size_t)bh * (2048 * 64);
  const short* Kg = kb + (size_t)bh * (2048 * 64);
  const short* Vg = vtb + (size_t)bh * (64 * 2048);

  // Q fragments: global -> registers once; B-operand layout (n=q on l16,
  // k = kc*32 + quad*8 + j contiguous d)
  short8 qf[2][2];
#pragma unroll
  for (int qt = 0; qt < 2; ++qt)
#pragma unroll
    for (int kc = 0; kc < 2; ++kc)
      qf[qt][kc] = *(const short8*)
          &Qg[(size_t)(q0 + wave * 32 + qt * 16 + l16) * 64 + kc * 32 + quad * 8];

  const int str = lane >> 3;
  const int sgc = ((lane & 7) ^ (str & 7)) * 8;   // chunk-of-8 swizzle (shorts)
  const int fsw = l16 & 7;
  const int c0 = wave * 2, c1 = wave * 2 + 1;

  // quad-exchange constants: src lane byte-addr for frag words.
  // addrA (words 0,1): s = 2*(quad&1); addrB (words 2,3): s = 2*(quad&1)+1.
  const int adA = ((lane & 16) ? 128 : 0) + l16 * 4;
  const int adB = adA + 64;
  const bool hiq = (lane & 32) != 0;              // dst quads 2,3 -> kvt odd

  // prologue: stage K/V tile 0 into buffer 0
  async16(Kg + (size_t)(c0 * 8 + str) * 64 + sgc, (char*)Ks[0] + c0 * 1024);
  async16(Kg + (size_t)(c1 * 8 + str) * 64 + sgc, (char*)Ks[0] + c1 * 1024);
  async16(Vg + (size_t)(c0 * 8 + str) * 2048 + sgc, (char*)Vs[0] + c0 * 1024);
  async16(Vg + (size_t)(c1 * 8 + str) * 2048 + sgc, (char*)Vs[0] + c1 * 1024);

  float lsum[2] = {0.f, 0.f};
  f32x4 oacc[2][4] = {};   // [qt][nt]; C/D: col(n=d)=l16, row(m=q)=quad*4+r

  for (int t = 0; t < 32; ++t) {
    // barrier FIRST: drains buf[t&1] loads (issued last iter / prologue,
    // overlapped with compute of t-1) and protects buffer reuse.
    __syncthreads();

    int kvn = (t + 1) * 64;
    if (kvn < 2048) {
      char* kd = (char*)Ks[(t + 1) & 1];
      char* vd = (char*)Vs[(t + 1) & 1];
      async16(Kg + (size_t)(kvn + c0 * 8 + str) * 64 + sgc, kd + c0 * 1024);
      async16(Kg + (size_t)(kvn + c1 * 8 + str) * 64 + sgc, kd + c1 * 1024);
      async16(Vg + (size_t)(c0 * 8 + str) * 2048 + kvn + sgc, vd + c0 * 1024);
      async16(Vg + (size_t)(c1 * 8 + str) * 2048 + kvn + sgc, vd + c1 * 1024);
    }
    const short* Kst = Ks[t & 1];
    const short* Vst = Vs[t & 1];

    // per 32-wide kv block: QK^T (4 MFMA/qt) -> exp2/pack -> quad-exchange
    // -> 2 K=32 f16 PV MFMA per (qt,nt)
#pragma unroll
    for (int blk = 0; blk < 2; ++blk) {
      f32x4 sacc[2][2] = {};   // [qt][vv], vv = kvt within block
#pragma unroll
      for (int kc = 0; kc < 2; ++kc) {
        short8 kf[2];
#pragma unroll
        for (int vv = 0; vv < 2; ++vv)
          kf[vv] = *(const short8*)
              &Kst[((blk * 2 + vv) * 16 + l16) * 64 + (((kc * 4 + quad) ^ fsw) << 3)];
#pragma unroll
        for (int vv = 0; vv < 2; ++vv)
#pragma unroll
          for (int qt = 0; qt < 2; ++qt)
            sacc[qt][vv] = __builtin_amdgcn_mfma_f32_16x16x32_bf16(
                kf[vv], qf[qt][kc], sacc[qt][vv], 0, 0, 0);
      }

      // exp2 + lsum + pack to f16 pairs: pk[qt][vv][u] holds
      // P[q=l16][kv=(2blk+vv)*16 + quad*4 + 2u + {0,1}]
      unsigned pk[2][2][2];
#pragma unroll
      for (int qt = 0; qt < 2; ++qt)
#pragma unroll
        for (int vv = 0; vv < 2; ++vv) {
          float p0 = EXP2F(sacc[qt][vv][0]);
          float p1 = EXP2F(sacc[qt][vv][1]);
          float p2 = EXP2F(sacc[qt][vv][2]);
          float p3 = EXP2F(sacc[qt][vv][3]);
          lsum[qt] += (p0 + p1) + (p2 + p3);
          pk[qt][vv][0] = pkh(p0, p1);
          pk[qt][vv][1] = pkh(p2, p3);
        }

      // quad-exchange -> K=32 A-frags (k = quad*8 + 2w + h)
      half8 pf[2];
#pragma unroll
      for (int qt = 0; qt < 2; ++qt) {
        int e0 = __builtin_amdgcn_ds_bpermute(adA, (int)pk[qt][0][0]);
        int o0 = __builtin_amdgcn_ds_bpermute(adA, (int)pk[qt][1][0]);
        int e1 = __builtin_amdgcn_ds_bpermute(adA, (int)pk[qt][0][1]);
        int o1 = __builtin_amdgcn_ds_bpermute(adA, (int)pk[qt][1][1]);
        int e2 = __builtin_amdgcn_ds_bpermute(adB, (int)pk[qt][0][0]);
        int o2 = __builtin_amdgcn_ds_bpermute(adB, (int)pk[qt][1][0]);
        int e3 = __builtin_amdgcn_ds_bpermute(adB, (int)pk[qt][0][1]);
        int o3 = __builtin_amdgcn_ds_bpermute(adB, (int)pk[qt][1][1]);
        uint4 wv;
        wv.x = (unsigned)(hiq ? o0 : e0);
        wv.y = (unsigned)(hiq ? o1 : e1);
        wv.z = (unsigned)(hiq ? o2 : e2);
        wv.w = (unsigned)(hiq ? o3 : e3);
        pf[qt] = __builtin_bit_cast(half8, wv);
      }

      // V B-frags: k = kv = blk*32 + quad*8 + j, n = d = nt*16 + l16;
      // Vs row d, chunk index (blk*4+quad) ^ fsw, 8 consecutive f16 (b128).
#pragma unroll
      for (int nt = 0; nt < 4; ++nt) {
        half8 vf = *(const half8*)
            &Vst[(nt * 16 + l16) * 64 + (((blk * 4 + quad) ^ fsw) << 3)];
#pragma unroll
        for (int qt = 0; qt < 2; ++qt)
          oacc[qt][nt] = __builtin_amdgcn_mfma_f32_16x16x32_f16(
              pf[qt], vf, oacc[qt][nt], 0, 0, 0);
      }
    }
    // no trailing barrier: next iteration's leading barrier covers reuse.
  }

  // final l reduction: lane has partial for q = qt*16+l16 over its quad's kv
#pragma unroll
  for (int qt = 0; qt < 2; ++qt) {
    float v = lsum[qt];
    v += __shfl_xor(v, 16, 64);
    v += __shfl_xor(v, 32, 64);
    if (quad == 0) Ls[wave][qt * 16 + l16] = v;
  }
  __asm__ volatile("s_waitcnt lgkmcnt(0)" ::: "memory");
  __builtin_amdgcn_wave_barrier();

  const int b = bh >> 4, h = bh & 15;
#pragma unroll
  for (int qt = 0; qt < 2; ++qt) {
    float4 lr = *(const float4*)&Ls[wave][qt * 16 + quad * 4];
    float inv0 = 1.f / lr.x, inv1 = 1.f / lr.y, inv2 = 1.f / lr.z, inv3 = 1.f / lr.w;
#pragma unroll
    for (int nt = 0; nt < 4; ++nt) {
      int d = nt * 16 + l16;
      int qbase = q0 + wave * 32 + qt * 16 + quad * 4;
      size_t obase = ((size_t)(b * 2048 + qbase)) * 1024 + h * 64 + d;
      ob[obase]        = f2bf(oacc[qt][nt][0] * inv0);
      ob[obase + 1024] = f2bf(oacc[qt][nt][1] * inv1);
      ob[obase + 2048] = f2bf(oacc[qt][nt][2] * inv2);
      ob[obase + 3072] = f2bf(oacc[qt][nt][3] * inv3);
    }
  }
}

// ----------------------------- launch --------------------------------------

extern "C" void kernel_launch(void* const* d_in, const int* in_sizes, int n_in,
                              void* d_out, int out_size, void* d_ws, size_t ws_size,
                              hipStream_t stream) {
  const float* x      = (const float*)d_in[0];
  const float* w_qkv  = (const float*)d_in[1];
  const float* b_qkv  = (const float*)d_in[2];
  const float* w_proj = (const float*)d_in[3];
  const float* b_proj = (const float*)d_in[4];
  float* out = (float*)d_out;

  short* xs     = (short*)d_ws;                     // [8192,1024]
  short* wqkvT  = xs + (size_t)8192 * 1024;         // [3072,1024]
  short* wprojT = wqkvT + (size_t)3072 * 1024;      // [1024,1024]
  short* qb     = wprojT + (size_t)1024 * 1024;     // [64,2048,64]
  short* kb     = qb + (size_t)64 * 2048 * 64;      // [64,2048,64]
  short* vtb    = kb + (size_t)64 * 2048 * 64;      // [64,64,2048] f16
  short* aob    = vtb + (size_t)64 * 2048 * 64;     // [8192,1024]

  convert_kernel<<<dim3(4096), 256, 0, stream>>>(x, xs);
  wtrans_kernel<<<dim3(96, 32), dim3(32, 8), 0, stream>>>(w_qkv, wqkvT, 1024, 3072);
  wtrans_kernel<<<dim3(32, 32), dim3(32, 8), 0, stream>>>(w_proj, wprojT, 1024, 1024);

  gemm_kernel<0><<<dim3(24, 32), 512, 0, stream>>>(xs, wqkvT, b_qkv, 3072,
                                                   qb, kb, vtb, nullptr);
  attn_kernel<<<dim3(16, 64), 256, 0, stream>>>(qb, kb, vtb, aob);
  gemm_kernel<1><<<dim3(8, 32), 512, 0, stream>>>(aob, wprojT, b_proj, 1024,
                                                  nullptr, nullptr, nullptr, out);
}

// Round 5
// 276.711 us; speedup vs baseline: 1.0548x; 1.0548x over previous
//
#include <hip/hip_runtime.h>
#include <cstdint>
#include <cstddef>

// ---------------------------------------------------------------------------
// MSA: out = proj(softmax(Q K^T * scale) V) for B=4, N=2048, C=1024, H=16, HD=64
// bf16/f16 MFMA pipeline:
//   1. convert x -> bf16                       [8192,1024]
//   2. transpose-convert w_qkv -> bf16 [3072,1024], w_proj -> bf16 [1024,1024]
//   3. GEMM qkv: 256x128 tile, 4 waves x (128x64 out), BK=32, TRIPLE-buffered
//      LDS (72 KB -> 2 blocks/CU), ONE raw barrier/K-tile, counted vmcnt(6):
//      stage t+2 while computing t; t+1's loads retire a full tile early.
//      Per-wave 32 MFMA / 12 ds_read_b128 per tile (2.67 ratio).
//      XCD/L2-aware block remap (XCD c owns contiguous m-panels).
//   4. attention (R3-proven 94.7us): 128 q/block, 4 waves x 32 q-rows,
//      BKV=64, S^T=K·Q^T, no-max softmax, p=exp2(s); S^T C-layout ==
//      A-layout of mfma_f32_16x16x16_f16 -> P feeds PV from registers.
//      K+V LDS double-buffered, 1 barrier/tile, 4 blocks/CU, bijective XCD
//      swizzle (FETCH 142->28 MB measured).
//   5. GEMM proj: same kernel, 128x128 tile -> fp32 d_out
// ---------------------------------------------------------------------------

typedef __attribute__((ext_vector_type(8))) short short8;   // 8 x bf16 (4 VGPRs)
typedef __attribute__((ext_vector_type(4))) float f32x4;    // MFMA C/D
typedef _Float16 half4 __attribute__((ext_vector_type(4))); // 16x16x16 A/B frag

#if __has_builtin(__builtin_amdgcn_exp2f)
#define EXP2F(x) __builtin_amdgcn_exp2f(x)
#else
#define EXP2F(x) __expf((x) * 0.69314718056f)
#endif

__device__ __forceinline__ short f2bf(float x) {            // RNE float->bf16 bits
  unsigned u = __builtin_bit_cast(unsigned, x);
  u += 0x7fffu + ((u >> 16) & 1u);
  return (short)(u >> 16);
}

__device__ __forceinline__ unsigned pkh(float a, float b) { // pack 2xf32 -> f16x2
  auto h = __builtin_amdgcn_cvt_pkrtz(a, b);                // __fp16 ext_vector(2)
  return __builtin_bit_cast(unsigned, h);
}

__device__ __forceinline__ void async16(const void* g, void* l) {
  // 16B per lane, LDS dest = wave-uniform base + lane*16
  __builtin_amdgcn_global_load_lds(
      (const __attribute__((address_space(1))) unsigned*)g,
      (__attribute__((address_space(3))) unsigned*)l, 16, 0, 0);
}

__device__ __forceinline__ void barrier_raw() {
  __asm__ volatile("" ::: "memory");
  __builtin_amdgcn_s_barrier();
  __asm__ volatile("" ::: "memory");
}

// ------------------------------- casts -------------------------------------

__global__ __launch_bounds__(256) void convert_kernel(const float* __restrict__ in,
                                                      short* __restrict__ out) {
  int i = blockIdx.x * 256 + threadIdx.x;          // 8 elems/thread
  const float4* p = (const float4*)in + (size_t)i * 2;
  float4 a = p[0], b = p[1];
  short8 r;
  r[0] = f2bf(a.x); r[1] = f2bf(a.y); r[2] = f2bf(a.z); r[3] = f2bf(a.w);
  r[4] = f2bf(b.x); r[5] = f2bf(b.y); r[6] = f2bf(b.z); r[7] = f2bf(b.w);
  *((short8*)out + i) = r;
}

// in: fp32 [K,N] row-major  ->  out: bf16 [N,K] row-major
__global__ __launch_bounds__(256) void wtrans_kernel(const float* __restrict__ in,
                                                     short* __restrict__ out,
                                                     int K, int N) {
  __shared__ float tile[32][33];
  int n0 = blockIdx.x * 32, k0 = blockIdx.y * 32;
  int tx = threadIdx.x, ty = threadIdx.y;          // block (32,8)
  for (int r = ty; r < 32; r += 8)
    tile[r][tx] = in[(size_t)(k0 + r) * N + n0 + tx];
  __syncthreads();
  for (int r = ty; r < 32; r += 8)
    out[(size_t)(n0 + r) * K + k0 + tx] = f2bf(tile[tx][r]);
}

// ------------------------------- GEMM --------------------------------------
// C[M,Nn] = A[M,1024] * Bt[Nn,1024]^T ; BM x BN block tile, BK=32, 4 waves
// as 2Mx2N, each wave (BM/2)x(BN/2) out = (BM/32)x(BN/32) 16x16x32 MFMA/tile.
// LDS: one [BM+BN][32]-short tile per buffer, chunk-of-4 (16B) XOR swizzle
// (chunk ^= row&3) applied at stage-source AND frag-read -> conflict-free
// b128 reads. TRIPLE buffered: while computing tile t, stage t+2; end-of-tile
// wait vmcnt(L) keeps t+2's L loads in flight (t+1's, a full tile older, are
// retired). ONE raw s_barrier per K-tile; no vmcnt(0) drain in the loop.
// Block remap: XCD c (id%8) owns m-panels [c*MC,(c+1)*MC); n in chunks of 8.
// MODE 0: QKV epilogue (bias, scale Q by SCALE*log2e, scatter q/k bf16, vT f16)
// MODE 1: proj epilogue (bias, fp32 out)

template <int BM, int BN, int MODE>
__global__ __launch_bounds__(256, 2) void gemm_kernel(
    const short* __restrict__ A, const short* __restrict__ Bt,
    const float* __restrict__ bias, int Nn,
    short* __restrict__ qb, short* __restrict__ kb, short* __restrict__ vtb,
    float* __restrict__ outp) {
  constexpr int K = 1024;
  constexpr int NT = K / 32;                       // 32 K-tiles
  constexpr int MR = BM / 32, NR = BN / 32;        // frags per wave
  constexpr int L = (BM + BN) / 64;                // async16 per thread per tile
  __shared__ __align__(16) short Ts[3][(BM + BN) * 32];
  const int tid = threadIdx.x, wave = tid >> 6, lane = tid & 63;
  const int quad = lane >> 4, l16 = lane & 15;

  // XCD/L2-aware remap: id -> (c = id%8, j = id/8); XCD c owns MC m-panels;
  // within, n in chunks of 8 (requires gridDim.x*gridDim.y % 8 == 0).
  const unsigned bid = blockIdx.x + gridDim.x * blockIdx.y;
  const unsigned c = bid & 7u, j = bid >> 3;
  const unsigned MC = gridDim.y >> 3;              // m-panels per XCD
  const unsigned chunk = MC * 8u;                  // blocks per n-chunk per XCD
  const unsigned nc = j / chunk, rem = j - nc * chunk;
  const unsigned m_idx = c * MC + (rem >> 3);
  const unsigned n_idx = nc * 8u + (rem & 7u);
  const int m0 = (int)m_idx * BM, n0 = (int)n_idx * BN;

  const int wrow = (wave >> 1) * (BM / 2), wcol = (wave & 1) * (BN / 2);

  // staging: row = i*64 + (tid>>2), 16B chunk = tid&3, src chunk XOR (row&3)
  const int srow = tid >> 2;
  const int sch8 = (((tid & 3) ^ (srow & 3)) * 8);          // shorts
  const short* Ag = A + (size_t)(m0 + srow) * K + sch8;
  const short* Bg = Bt + (size_t)(n0 + srow) * K + sch8;
  const int fq8 = ((quad ^ (l16 & 3)) * 8);                 // frag chunk (shorts)

  f32x4 acc[MR][NR] = {};

  auto stage = [&](int b, int kt) {
    char* dst = (char*)Ts[b] + tid * 16;
#pragma unroll
    for (int i = 0; i < BM / 64; ++i)
      async16(Ag + (size_t)(i * 64) * K + kt * 32, dst + i * 4096);
#pragma unroll
    for (int i = 0; i < BN / 64; ++i)
      async16(Bg + (size_t)(i * 64) * K + kt * 32, dst + (BM / 64 + i) * 4096);
  };

  // prologue: stage tiles 0,1 into bufs 0,1; wait tile 0 (keep 1 in flight)
  stage(0, 0);
  stage(1, 1);
  if constexpr (L == 6) asm volatile("s_waitcnt vmcnt(6)" ::: "memory");
  else                  asm volatile("s_waitcnt vmcnt(4)" ::: "memory");
  barrier_raw();

  int cb = 0, sb = 2;
  for (int t = 0; t < NT; ++t) {
    if (t + 2 < NT) stage(sb, t + 2);

    const short* Tb = Ts[cb];
    short8 af[MR], bf[NR];
#pragma unroll
    for (int mf = 0; mf < MR; ++mf)
      af[mf] = *(const short8*)&Tb[(wrow + mf * 16 + l16) * 32 + fq8];
#pragma unroll
    for (int nf = 0; nf < NR; ++nf)
      bf[nf] = *(const short8*)&Tb[(BM + wcol + nf * 16 + l16) * 32 + fq8];

    __builtin_amdgcn_s_setprio(1);
#pragma unroll
    for (int mf = 0; mf < MR; ++mf)
#pragma unroll
      for (int nf = 0; nf < NR; ++nf)
        acc[mf][nf] = __builtin_amdgcn_mfma_f32_16x16x32_bf16(
            af[mf], bf[nf], acc[mf][nf], 0, 0, 0);
    __builtin_amdgcn_s_setprio(0);

    // counted wait: keep t+2's L loads in flight; t+1's (a tile old) retired.
    if (t + 2 < NT) {
      if constexpr (L == 6) asm volatile("s_waitcnt vmcnt(6)" ::: "memory");
      else                  asm volatile("s_waitcnt vmcnt(4)" ::: "memory");
    } else {
      asm volatile("s_waitcnt vmcnt(0)" ::: "memory");
    }
    barrier_raw();
    cb = cb + 1; if (cb >= 3) cb -= 3;
    sb = sb + 1; if (sb >= 3) sb -= 3;
  }

  // epilogue: C/D layout col = l16, row = quad*4 + reg
  if (MODE == 0) {
#pragma unroll
    for (int mf = 0; mf < MR; ++mf) {
      int row0 = m0 + wrow + mf * 16 + quad * 4;
      int b = row0 >> 11, n = row0 & 2047;
#pragma unroll
      for (int nf = 0; nf < NR; ++nf) {
        int col = n0 + wcol + nf * 16 + l16;
        float bv = bias[col];
        float v0 = acc[mf][nf][0] + bv, v1 = acc[mf][nf][1] + bv;
        float v2 = acc[mf][nf][2] + bv, v3 = acc[mf][nf][3] + bv;
        int which = col >> 10;
        int h = (col >> 6) & 15;
        int d = col & 63;
        size_t bh = (size_t)(b * 16 + h);
        if (which == 0) {             // Q, pre-scaled by SCALE*log2(e)
          const float qs = 0.18033688f;   // 0.125 * 1.44269504
          size_t base = (bh * 2048 + n) * 64 + d;
          qb[base]       = f2bf(v0 * qs);
          qb[base + 64]  = f2bf(v1 * qs);
          qb[base + 128] = f2bf(v2 * qs);
          qb[base + 192] = f2bf(v3 * qs);
        } else if (which == 1) {      // K
          size_t base = (bh * 2048 + n) * 64 + d;
          kb[base]       = f2bf(v0);
          kb[base + 64]  = f2bf(v1);
          kb[base + 128] = f2bf(v2);
          kb[base + 192] = f2bf(v3);
        } else {                      // V transposed: [bh, d, n] f16, 4 tokens
          uint2 pk;
          pk.x = pkh(v0, v1);
          pk.y = pkh(v2, v3);
          *(uint2*)&vtb[(bh * 64 + d) * 2048 + n] = pk;
        }
      }
    }
  } else {
#pragma unroll
    for (int mf = 0; mf < MR; ++mf) {
      int row0 = m0 + wrow + mf * 16 + quad * 4;
#pragma unroll
      for (int nf = 0; nf < NR; ++nf) {
        int col = n0 + wcol + nf * 16 + l16;
        float bv = bias[col];
        outp[(size_t)row0 * Nn + col]       = acc[mf][nf][0] + bv;
        outp[(size_t)(row0 + 1) * Nn + col] = acc[mf][nf][1] + bv;
        outp[(size_t)(row0 + 2) * Nn + col] = acc[mf][nf][2] + bv;
        outp[(size_t)(row0 + 3) * Nn + col] = acc[mf][nf][3] + bv;
      }
    }
  }
}

// ----------------------------- attention -----------------------------------
// One block = one (b,h) x 128 q-rows; 4 waves, 32 q-rows each. BKV = 64.
// Q pre-scaled by SCALE*log2e. qb/kb: [BH,2048,64] bf16; vtb: [BH,64,2048] f16.
// S^T = K Q^T via 16x16x32 bf16 (A=K m=kv, B=Q n=q): lane holds
// q=qt*16+l16, kv=kvt*16+quad*4+r — which IS the A-layout of
// mfma_f32_16x16x16_f16 (m=l16, k=quad*4+j) for k-block kvt. So P goes
// exp2 -> pkrtz -> straight into PV MFMA from registers. V B-frags (n=d,
// k=quad*4+j consecutive kv) are ds_read_b64 from the swizzled Vs tile.
// K+V double-buffered, barrier-first prefetch, 1 barrier/tile, 4 blocks/CU.
// Bijective XCD swizzle: XCD c covers bh in [8c,8c+8) -> K/V set 4MB = L2
// (measured R2: FETCH 142 -> 33 MB).
// ob: [B, 2048, 1024] bf16 attention output.

__global__ __launch_bounds__(256, 4) void attn_kernel(
    const short* __restrict__ qb, const short* __restrict__ kb,
    const short* __restrict__ vtb, short* __restrict__ ob) {
  __shared__ __align__(16) short Ks[2][64 * 64];  // bf16 [kv][d]
  __shared__ __align__(16) short Vs[2][64 * 64];  // f16  [d][kv]
  __shared__ __align__(16) float Ls[4][32];
  const int tid = threadIdx.x, wave = tid >> 6, lane = tid & 63;
  const int quad = lane >> 4, l16 = lane & 15;
  // XCD-bijective remap: linear id n -> n' = (n%8)*128 + n/8, so XCD c
  // (blocks n with n%8==c under round-robin dispatch) covers bh in [8c,8c+8).
  int nlin = blockIdx.x + blockIdx.y * 16;
  nlin = (nlin & 7) * 128 + (nlin >> 3);
  const int q0 = (nlin & 15) * 128;
  const int bh = nlin >> 4;
  const short* Qg = qb + (size_t)bh * (2048 * 64);
  const short* Kg = kb + (size_t)bh * (2048 * 64);
  const short* Vg = vtb + (size_t)bh * (64 * 2048);

  // Q fragments: global -> registers once; B-operand layout (n=q on l16,
  // k = kc*32 + quad*8 + j contiguous d)
  short8 qf[2][2];
#pragma unroll
  for (int qt = 0; qt < 2; ++qt)
#pragma unroll
    for (int kc = 0; kc < 2; ++kc)
      qf[qt][kc] = *(const short8*)
          &Qg[(size_t)(q0 + wave * 32 + qt * 16 + l16) * 64 + kc * 32 + quad * 8];

  const int str = lane >> 3;
  const int sgc = ((lane & 7) ^ (str & 7)) * 8;   // chunk-of-8 swizzle (shorts)
  const int fsw = l16 & 7;
  const int c0 = wave * 2, c1 = wave * 2 + 1;

  // prologue: stage K/V tile 0 into buffer 0
  async16(Kg + (size_t)(c0 * 8 + str) * 64 + sgc, (char*)Ks[0] + c0 * 1024);
  async16(Kg + (size_t)(c1 * 8 + str) * 64 + sgc, (char*)Ks[0] + c1 * 1024);
  async16(Vg + (size_t)(c0 * 8 + str) * 2048 + sgc, (char*)Vs[0] + c0 * 1024);
  async16(Vg + (size_t)(c1 * 8 + str) * 2048 + sgc, (char*)Vs[0] + c1 * 1024);

  float lsum[2] = {0.f, 0.f};
  f32x4 oacc[2][4] = {};   // [qt][nt]; C/D: col(n=d)=l16, row(m=q)=quad*4+r

  for (int t = 0; t < 32; ++t) {
    // barrier FIRST: drains buf[t&1] loads (issued last iter / prologue,
    // overlapped with compute of t-1) and protects buffer reuse.
    __syncthreads();

    int kvn = (t + 1) * 64;
    if (kvn < 2048) {
      char* kd = (char*)Ks[(t + 1) & 1];
      char* vd = (char*)Vs[(t + 1) & 1];
      async16(Kg + (size_t)(kvn + c0 * 8 + str) * 64 + sgc, kd + c0 * 1024);
      async16(Kg + (size_t)(kvn + c1 * 8 + str) * 64 + sgc, kd + c1 * 1024);
      async16(Vg + (size_t)(c0 * 8 + str) * 2048 + kvn + sgc, vd + c0 * 1024);
      async16(Vg + (size_t)(c1 * 8 + str) * 2048 + kvn + sgc, vd + c1 * 1024);
    }
    const short* Kst = Ks[t & 1];
    const short* Vst = Vs[t & 1];

    // S^T = K Q^T  (16x16x32 bf16)
    f32x4 sacc[2][4] = {};   // [qt][kvt]
#pragma unroll
    for (int kc = 0; kc < 2; ++kc) {
      short8 kf[4];
#pragma unroll
      for (int kvt = 0; kvt < 4; ++kvt)
        kf[kvt] = *(const short8*)
            &Kst[(kvt * 16 + l16) * 64 + (((kc * 4 + quad) ^ fsw) << 3)];
#pragma unroll
      for (int kvt = 0; kvt < 4; ++kvt)
#pragma unroll
        for (int qt = 0; qt < 2; ++qt)
          sacc[qt][kvt] = __builtin_amdgcn_mfma_f32_16x16x32_bf16(
              kf[kvt], qf[qt][kc], sacc[qt][kvt], 0, 0, 0);
    }

    // per k-block kvt: p = exp2(s) -> pkrtz -> A-frag; V B-frag b64; PV MFMA
#pragma unroll
    for (int kvt = 0; kvt < 4; ++kvt) {
      half4 pfr[2];
#pragma unroll
      for (int qt = 0; qt < 2; ++qt) {
        float p0 = EXP2F(sacc[qt][kvt][0]);
        float p1 = EXP2F(sacc[qt][kvt][1]);
        float p2 = EXP2F(sacc[qt][kvt][2]);
        float p3 = EXP2F(sacc[qt][kvt][3]);
        lsum[qt] += (p0 + p1) + (p2 + p3);
        uint2 w;
        w.x = pkh(p0, p1);
        w.y = pkh(p2, p3);
        pfr[qt] = __builtin_bit_cast(half4, w);
      }
      // V B-frag: k = kv = kvt*16 + quad*4 + j, n = d = nt*16 + l16;
      // Vs row d stored with chunk-of-8 swizzle keyed on d&7 (= fsw).
      const int vcol = (((kvt * 2 + (quad >> 1)) ^ fsw) << 3) + (quad & 1) * 4;
#pragma unroll
      for (int nt = 0; nt < 4; ++nt) {
        uint2 vr = *(const uint2*)&Vst[(nt * 16 + l16) * 64 + vcol];
        half4 vfr = __builtin_bit_cast(half4, vr);
#pragma unroll
        for (int qt = 0; qt < 2; ++qt)
          oacc[qt][nt] = __builtin_amdgcn_mfma_f32_16x16x16f16(
              pfr[qt], vfr, oacc[qt][nt], 0, 0, 0);
      }
    }
    // no trailing barrier: next iteration's leading barrier covers reuse.
  }

  // final l reduction: lane has partial for q = qt*16+l16 over its quad's kv
#pragma unroll
  for (int qt = 0; qt < 2; ++qt) {
    float v = lsum[qt];
    v += __shfl_xor(v, 16, 64);
    v += __shfl_xor(v, 32, 64);
    if (quad == 0) Ls[wave][qt * 16 + l16] = v;
  }
  __asm__ volatile("s_waitcnt lgkmcnt(0)" ::: "memory");
  __builtin_amdgcn_wave_barrier();

  const int b = bh >> 4, h = bh & 15;
#pragma unroll
  for (int qt = 0; qt < 2; ++qt) {
    float4 lr = *(const float4*)&Ls[wave][qt * 16 + quad * 4];
    float inv0 = 1.f / lr.x, inv1 = 1.f / lr.y, inv2 = 1.f / lr.z, inv3 = 1.f / lr.w;
#pragma unroll
    for (int nt = 0; nt < 4; ++nt) {
      int d = nt * 16 + l16;
      int qbase = q0 + wave * 32 + qt * 16 + quad * 4;
      size_t obase = ((size_t)(b * 2048 + qbase)) * 1024 + h * 64 + d;
      ob[obase]        = f2bf(oacc[qt][nt][0] * inv0);
      ob[obase + 1024] = f2bf(oacc[qt][nt][1] * inv1);
      ob[obase + 2048] = f2bf(oacc[qt][nt][2] * inv2);
      ob[obase + 3072] = f2bf(oacc[qt][nt][3] * inv3);
    }
  }
}

// ----------------------------- launch --------------------------------------

extern "C" void kernel_launch(void* const* d_in, const int* in_sizes, int n_in,
                              void* d_out, int out_size, void* d_ws, size_t ws_size,
                              hipStream_t stream) {
  const float* x      = (const float*)d_in[0];
  const float* w_qkv  = (const float*)d_in[1];
  const float* b_qkv  = (const float*)d_in[2];
  const float* w_proj = (const float*)d_in[3];
  const float* b_proj = (const float*)d_in[4];
  float* out = (float*)d_out;

  short* xs     = (short*)d_ws;                     // [8192,1024]
  short* wqkvT  = xs + (size_t)8192 * 1024;         // [3072,1024]
  short* wprojT = wqkvT + (size_t)3072 * 1024;      // [1024,1024]
  short* qb     = wprojT + (size_t)1024 * 1024;     // [64,2048,64]
  short* kb     = qb + (size_t)64 * 2048 * 64;      // [64,2048,64]
  short* vtb    = kb + (size_t)64 * 2048 * 64;      // [64,64,2048] f16
  short* aob    = vtb + (size_t)64 * 2048 * 64;     // [8192,1024]

  convert_kernel<<<dim3(4096), 256, 0, stream>>>(x, xs);
  wtrans_kernel<<<dim3(96, 32), dim3(32, 8), 0, stream>>>(w_qkv, wqkvT, 1024, 3072);
  wtrans_kernel<<<dim3(32, 32), dim3(32, 8), 0, stream>>>(w_proj, wprojT, 1024, 1024);

  gemm_kernel<256, 128, 0><<<dim3(24, 32), 256, 0, stream>>>(
      xs, wqkvT, b_qkv, 3072, qb, kb, vtb, nullptr);
  attn_kernel<<<dim3(16, 64), 256, 0, stream>>>(qb, kb, vtb, aob);
  gemm_kernel<128, 128, 1><<<dim3(8, 64), 256, 0, stream>>>(
      aob, wprojT, b_proj, 1024, nullptr, nullptr, nullptr, out);
}

// Round 6
// 267.095 us; speedup vs baseline: 1.0927x; 1.0360x over previous
//
#include <hip/hip_runtime.h>
#include <cstdint>
#include <cstddef>

// ---------------------------------------------------------------------------
// MSA: out = proj(softmax(Q K^T * scale) V) for B=4, N=2048, C=1024, H=16, HD=64
// bf16/f16 MFMA pipeline:
//   1. prep (ONE dispatch): x -> bf16; transpose-convert w_qkv, w_proj.
//   2. GEMM qkv: 256x128 tile, 4 waves x (128x64 out), BK=32, triple-buffered
//      LDS (2 blocks/CU), one raw barrier/K-tile, counted vmcnt.
//      XCD/L2-aware block remap.
//   3. attention: 128 q/block, 4 waves x 32 q-rows, BKV=64, S^T=K·Q^T,
//      no-max softmax, p=exp2(s); S^T C-layout == A-layout of
//      mfma_f32_16x16x16_f16 -> P feeds PV from registers.
//      NEW: softmax denominator via ones-B MFMA (lacc) -> no VALU lsum, no
//      shfl/LDS epilogue (lane holds denom for exactly its output rows);
//      hoisted zero-C for QK^T; V b64 reads hoisted under the exp2 chain
//      (4-way bank aliasing at 128B row stride can only be hidden).
//      K+V LDS double-buffered, 1 barrier/tile, 4 blocks/CU, bijective XCD
//      swizzle (FETCH 142->28 MB measured).
//   4. GEMM proj: same kernel, 128x128 tile -> fp32 d_out
// ---------------------------------------------------------------------------

typedef __attribute__((ext_vector_type(8))) short short8;   // 8 x bf16 (4 VGPRs)
typedef __attribute__((ext_vector_type(4))) float f32x4;    // MFMA C/D
typedef _Float16 half4 __attribute__((ext_vector_type(4))); // 16x16x16 A/B frag

#if __has_builtin(__builtin_amdgcn_exp2f)
#define EXP2F(x) __builtin_amdgcn_exp2f(x)
#else
#define EXP2F(x) __expf((x) * 0.69314718056f)
#endif

__device__ __forceinline__ short f2bf(float x) {            // RNE float->bf16 bits
  unsigned u = __builtin_bit_cast(unsigned, x);
  u += 0x7fffu + ((u >> 16) & 1u);
  return (short)(u >> 16);
}

__device__ __forceinline__ unsigned pkh(float a, float b) { // pack 2xf32 -> f16x2
  auto h = __builtin_amdgcn_cvt_pkrtz(a, b);                // __fp16 ext_vector(2)
  return __builtin_bit_cast(unsigned, h);
}

__device__ __forceinline__ void async16(const void* g, void* l) {
  // 16B per lane, LDS dest = wave-uniform base + lane*16
  __builtin_amdgcn_global_load_lds(
      (const __attribute__((address_space(1))) unsigned*)g,
      (__attribute__((address_space(3))) unsigned*)l, 16, 0, 0);
}

__device__ __forceinline__ void barrier_raw() {
  __asm__ volatile("" ::: "memory");
  __builtin_amdgcn_s_barrier();
  __asm__ volatile("" ::: "memory");
}

// ------------------------------- prep --------------------------------------
// One dispatch: blocks [0,4096) convert x; [4096,7168) transpose w_qkv;
// [7168,8192) transpose w_proj. Branch is block-uniform; barriers legal.

__global__ __launch_bounds__(256) void prep_kernel(
    const float* __restrict__ x, const float* __restrict__ w_qkv,
    const float* __restrict__ w_proj, short* __restrict__ xs,
    short* __restrict__ wqkvT, short* __restrict__ wprojT) {
  __shared__ float tile[32][33];
  const int bid = blockIdx.x, tid = threadIdx.x;
  if (bid < 4096) {                                // x -> bf16, 8 elems/thread
    int i = bid * 256 + tid;
    const float4* p = (const float4*)x + (size_t)i * 2;
    float4 a = p[0], b = p[1];
    short8 r;
    r[0] = f2bf(a.x); r[1] = f2bf(a.y); r[2] = f2bf(a.z); r[3] = f2bf(a.w);
    r[4] = f2bf(b.x); r[5] = f2bf(b.y); r[6] = f2bf(b.z); r[7] = f2bf(b.w);
    *((short8*)xs + i) = r;
    return;
  }
  const float* in;
  short* out;
  int N, bx, by;
  if (bid < 4096 + 3072) {
    int b = bid - 4096;
    in = w_qkv; out = wqkvT; N = 3072; bx = b % 96; by = b / 96;
  } else {
    int b = bid - 7168;
    in = w_proj; out = wprojT; N = 1024; bx = b & 31; by = b >> 5;
  }
  const int K = 1024;
  int n0 = bx * 32, k0 = by * 32;
  int tx = tid & 31, ty = tid >> 5;                // (32,8)
  for (int r = ty; r < 32; r += 8)
    tile[r][tx] = in[(size_t)(k0 + r) * N + n0 + tx];
  __syncthreads();
  for (int r = ty; r < 32; r += 8)
    out[(size_t)(n0 + r) * K + k0 + tx] = f2bf(tile[tx][r]);
}

// ------------------------------- GEMM --------------------------------------
// C[M,Nn] = A[M,1024] * Bt[Nn,1024]^T ; BM x BN block tile, BK=32, 4 waves
// as 2Mx2N, each wave (BM/2)x(BN/2) out = (BM/32)x(BN/32) 16x16x32 MFMA/tile.
// LDS: one [BM+BN][32]-short tile per buffer, chunk-of-4 (16B) XOR swizzle
// applied at stage-source AND frag-read -> conflict-free b128 reads.
// TRIPLE buffered: while computing tile t, stage t+2; end-of-tile wait
// vmcnt(L) keeps t+2's L loads in flight. ONE raw s_barrier per K-tile.
// Block remap: XCD c (id%8) owns m-panels [c*MC,(c+1)*MC); n in chunks of 8.
// MODE 0: QKV epilogue (bias, scale Q by SCALE*log2e, scatter q/k bf16, vT f16)
// MODE 1: proj epilogue (bias, fp32 out)

template <int BM, int BN, int MODE>
__global__ __launch_bounds__(256, 2) void gemm_kernel(
    const short* __restrict__ A, const short* __restrict__ Bt,
    const float* __restrict__ bias, int Nn,
    short* __restrict__ qb, short* __restrict__ kb, short* __restrict__ vtb,
    float* __restrict__ outp) {
  constexpr int K = 1024;
  constexpr int NT = K / 32;                       // 32 K-tiles
  constexpr int MR = BM / 32, NR = BN / 32;        // frags per wave
  constexpr int L = (BM + BN) / 64;                // async16 per thread per tile
  __shared__ __align__(16) short Ts[3][(BM + BN) * 32];
  const int tid = threadIdx.x, wave = tid >> 6, lane = tid & 63;
  const int quad = lane >> 4, l16 = lane & 15;

  // XCD/L2-aware remap: id -> (c = id%8, j = id/8); XCD c owns MC m-panels;
  // within, n in chunks of 8 (requires gridDim.x*gridDim.y % 8 == 0).
  const unsigned bid = blockIdx.x + gridDim.x * blockIdx.y;
  const unsigned c = bid & 7u, j = bid >> 3;
  const unsigned MC = gridDim.y >> 3;              // m-panels per XCD
  const unsigned chunk = MC * 8u;                  // blocks per n-chunk per XCD
  const unsigned nc = j / chunk, rem = j - nc * chunk;
  const unsigned m_idx = c * MC + (rem >> 3);
  const unsigned n_idx = nc * 8u + (rem & 7u);
  const int m0 = (int)m_idx * BM, n0 = (int)n_idx * BN;

  const int wrow = (wave >> 1) * (BM / 2), wcol = (wave & 1) * (BN / 2);

  // staging: row = i*64 + (tid>>2), 16B chunk = tid&3, src chunk XOR (row&3)
  const int srow = tid >> 2;
  const int sch8 = (((tid & 3) ^ (srow & 3)) * 8);          // shorts
  const short* Ag = A + (size_t)(m0 + srow) * K + sch8;
  const short* Bg = Bt + (size_t)(n0 + srow) * K + sch8;
  const int fq8 = ((quad ^ (l16 & 3)) * 8);                 // frag chunk (shorts)

  f32x4 acc[MR][NR] = {};

  auto stage = [&](int b, int kt) {
    char* dst = (char*)Ts[b] + tid * 16;
#pragma unroll
    for (int i = 0; i < BM / 64; ++i)
      async16(Ag + (size_t)(i * 64) * K + kt * 32, dst + i * 4096);
#pragma unroll
    for (int i = 0; i < BN / 64; ++i)
      async16(Bg + (size_t)(i * 64) * K + kt * 32, dst + (BM / 64 + i) * 4096);
  };

  // prologue: stage tiles 0,1 into bufs 0,1; wait tile 0 (keep 1 in flight)
  stage(0, 0);
  stage(1, 1);
  if constexpr (L == 6) asm volatile("s_waitcnt vmcnt(6)" ::: "memory");
  else                  asm volatile("s_waitcnt vmcnt(4)" ::: "memory");
  barrier_raw();

  int cb = 0, sb = 2;
  for (int t = 0; t < NT; ++t) {
    if (t + 2 < NT) stage(sb, t + 2);

    const short* Tb = Ts[cb];
    short8 af[MR], bf[NR];
#pragma unroll
    for (int mf = 0; mf < MR; ++mf)
      af[mf] = *(const short8*)&Tb[(wrow + mf * 16 + l16) * 32 + fq8];
#pragma unroll
    for (int nf = 0; nf < NR; ++nf)
      bf[nf] = *(const short8*)&Tb[(BM + wcol + nf * 16 + l16) * 32 + fq8];

    __builtin_amdgcn_s_setprio(1);
#pragma unroll
    for (int mf = 0; mf < MR; ++mf)
#pragma unroll
      for (int nf = 0; nf < NR; ++nf)
        acc[mf][nf] = __builtin_amdgcn_mfma_f32_16x16x32_bf16(
            af[mf], bf[nf], acc[mf][nf], 0, 0, 0);
    __builtin_amdgcn_s_setprio(0);

    // counted wait: keep t+2's L loads in flight; t+1's (a tile old) retired.
    if (t + 2 < NT) {
      if constexpr (L == 6) asm volatile("s_waitcnt vmcnt(6)" ::: "memory");
      else                  asm volatile("s_waitcnt vmcnt(4)" ::: "memory");
    } else {
      asm volatile("s_waitcnt vmcnt(0)" ::: "memory");
    }
    barrier_raw();
    cb = cb + 1; if (cb >= 3) cb -= 3;
    sb = sb + 1; if (sb >= 3) sb -= 3;
  }

  // epilogue: C/D layout col = l16, row = quad*4 + reg
  if (MODE == 0) {
#pragma unroll
    for (int mf = 0; mf < MR; ++mf) {
      int row0 = m0 + wrow + mf * 16 + quad * 4;
      int b = row0 >> 11, n = row0 & 2047;
#pragma unroll
      for (int nf = 0; nf < NR; ++nf) {
        int col = n0 + wcol + nf * 16 + l16;
        float bv = bias[col];
        float v0 = acc[mf][nf][0] + bv, v1 = acc[mf][nf][1] + bv;
        float v2 = acc[mf][nf][2] + bv, v3 = acc[mf][nf][3] + bv;
        int which = col >> 10;
        int h = (col >> 6) & 15;
        int d = col & 63;
        size_t bh = (size_t)(b * 16 + h);
        if (which == 0) {             // Q, pre-scaled by SCALE*log2(e)
          const float qs = 0.18033688f;   // 0.125 * 1.44269504
          size_t base = (bh * 2048 + n) * 64 + d;
          qb[base]       = f2bf(v0 * qs);
          qb[base + 64]  = f2bf(v1 * qs);
          qb[base + 128] = f2bf(v2 * qs);
          qb[base + 192] = f2bf(v3 * qs);
        } else if (which == 1) {      // K
          size_t base = (bh * 2048 + n) * 64 + d;
          kb[base]       = f2bf(v0);
          kb[base + 64]  = f2bf(v1);
          kb[base + 128] = f2bf(v2);
          kb[base + 192] = f2bf(v3);
        } else {                      // V transposed: [bh, d, n] f16, 4 tokens
          uint2 pk;
          pk.x = pkh(v0, v1);
          pk.y = pkh(v2, v3);
          *(uint2*)&vtb[(bh * 64 + d) * 2048 + n] = pk;
        }
      }
    }
  } else {
#pragma unroll
    for (int mf = 0; mf < MR; ++mf) {
      int row0 = m0 + wrow + mf * 16 + quad * 4;
#pragma unroll
      for (int nf = 0; nf < NR; ++nf) {
        int col = n0 + wcol + nf * 16 + l16;
        float bv = bias[col];
        outp[(size_t)row0 * Nn + col]       = acc[mf][nf][0] + bv;
        outp[(size_t)(row0 + 1) * Nn + col] = acc[mf][nf][1] + bv;
        outp[(size_t)(row0 + 2) * Nn + col] = acc[mf][nf][2] + bv;
        outp[(size_t)(row0 + 3) * Nn + col] = acc[mf][nf][3] + bv;
      }
    }
  }
}

// ----------------------------- attention -----------------------------------
// One block = one (b,h) x 128 q-rows; 4 waves, 32 q-rows each. BKV = 64.
// Q pre-scaled by SCALE*log2e. qb/kb: [BH,2048,64] bf16; vtb: [BH,64,2048] f16.
// S^T = K Q^T via 16x16x32 bf16 (A=K m=kv, B=Q n=q): lane holds
// q=qt*16+l16, kv=kvt*16+quad*4+r — the A-layout of mfma_f32_16x16x16_f16
// (m=l16, k=quad*4+j). P: exp2 -> pkrtz -> PV MFMA from registers.
// Softmax denominator: lacc[qt] = mfma(pfr[qt], ones) accumulates
// sum_k P[q][k]; C-layout row = quad*4+r == exactly the rows this lane
// writes in the epilogue -> no shfl reduce, no LDS round-trip.
// V b64 reads hoisted before the exp2 chain (their 4-way bank aliasing at
// 128-B row stride is structural; hide it under ~256cyc of transcendentals).
// K+V double-buffered, barrier-first prefetch, 1 barrier/tile, 4 blocks/CU.
// Bijective XCD swizzle: XCD c covers bh in [8c,8c+8) -> K/V set 4MB = L2.
// ob: [B, 2048, 1024] bf16 attention output.

__global__ __launch_bounds__(256, 4) void attn_kernel(
    const short* __restrict__ qb, const short* __restrict__ kb,
    const short* __restrict__ vtb, short* __restrict__ ob) {
  __shared__ __align__(16) short Ks[2][64 * 64];  // bf16 [kv][d]
  __shared__ __align__(16) short Vs[2][64 * 64];  // f16  [d][kv]
  const int tid = threadIdx.x, wave = tid >> 6, lane = tid & 63;
  const int quad = lane >> 4, l16 = lane & 15;
  // XCD-bijective remap: linear id n -> n' = (n%8)*128 + n/8, so XCD c
  // (blocks n with n%8==c under round-robin dispatch) covers bh in [8c,8c+8).
  int nlin = blockIdx.x + blockIdx.y * 16;
  nlin = (nlin & 7) * 128 + (nlin >> 3);
  const int q0 = (nlin & 15) * 128;
  const int bh = nlin >> 4;
  const short* Qg = qb + (size_t)bh * (2048 * 64);
  const short* Kg = kb + (size_t)bh * (2048 * 64);
  const short* Vg = vtb + (size_t)bh * (64 * 2048);

  // Q fragments: global -> registers once; B-operand layout (n=q on l16,
  // k = kc*32 + quad*8 + j contiguous d)
  short8 qf[2][2];
#pragma unroll
  for (int qt = 0; qt < 2; ++qt)
#pragma unroll
    for (int kc = 0; kc < 2; ++kc)
      qf[qt][kc] = *(const short8*)
          &Qg[(size_t)(q0 + wave * 32 + qt * 16 + l16) * 64 + kc * 32 + quad * 8];

  const int str = lane >> 3;
  const int sgc = ((lane & 7) ^ (str & 7)) * 8;   // chunk-of-8 swizzle (shorts)
  const int fsw = l16 & 7;
  const int c0 = wave * 2, c1 = wave * 2 + 1;

  // prologue: stage K/V tile 0 into buffer 0
  async16(Kg + (size_t)(c0 * 8 + str) * 64 + sgc, (char*)Ks[0] + c0 * 1024);
  async16(Kg + (size_t)(c1 * 8 + str) * 64 + sgc, (char*)Ks[0] + c1 * 1024);
  async16(Vg + (size_t)(c0 * 8 + str) * 2048 + sgc, (char*)Vs[0] + c0 * 1024);
  async16(Vg + (size_t)(c1 * 8 + str) * 2048 + sgc, (char*)Vs[0] + c1 * 1024);

  const half4 vone = {(_Float16)1.f, (_Float16)1.f, (_Float16)1.f, (_Float16)1.f};
  const f32x4 fz = {};                           // hoisted zero C-operand
  f32x4 oacc[2][4] = {};   // [qt][nt]; C/D: col(n=d)=l16, row(m=q)=quad*4+r
  f32x4 lacc[2] = {};      // [qt]; denom for q = qt*16 + quad*4 + r

  for (int t = 0; t < 32; ++t) {
    // barrier FIRST: drains buf[t&1] loads (issued last iter / prologue,
    // overlapped with compute of t-1) and protects buffer reuse.
    __syncthreads();

    int kvn = (t + 1) * 64;
    if (kvn < 2048) {
      char* kd = (char*)Ks[(t + 1) & 1];
      char* vd = (char*)Vs[(t + 1) & 1];
      async16(Kg + (size_t)(kvn + c0 * 8 + str) * 64 + sgc, kd + c0 * 1024);
      async16(Kg + (size_t)(kvn + c1 * 8 + str) * 64 + sgc, kd + c1 * 1024);
      async16(Vg + (size_t)(c0 * 8 + str) * 2048 + kvn + sgc, vd + c0 * 1024);
      async16(Vg + (size_t)(c1 * 8 + str) * 2048 + kvn + sgc, vd + c1 * 1024);
    }
    const short* Kst = Ks[t & 1];
    const short* Vst = Vs[t & 1];

    // S^T = K Q^T  (16x16x32 bf16); first kc consumes hoisted zero C.
    f32x4 sacc[2][4];
#pragma unroll
    for (int kc = 0; kc < 2; ++kc) {
      short8 kf[4];
#pragma unroll
      for (int kvt = 0; kvt < 4; ++kvt)
        kf[kvt] = *(const short8*)
            &Kst[(kvt * 16 + l16) * 64 + (((kc * 4 + quad) ^ fsw) << 3)];
#pragma unroll
      for (int kvt = 0; kvt < 4; ++kvt)
#pragma unroll
        for (int qt = 0; qt < 2; ++qt)
          sacc[qt][kvt] = __builtin_amdgcn_mfma_f32_16x16x32_bf16(
              kf[kvt], qf[qt][kc], kc == 0 ? fz : sacc[qt][kvt], 0, 0, 0);
    }

    // per k-block kvt: V reads FIRST (conflict latency hides under exp2),
    // then p = exp2(s) -> pkrtz -> A-frag; PV MFMA + ones-MFMA denom.
#pragma unroll
    for (int kvt = 0; kvt < 4; ++kvt) {
      // V B-frag: k = kv = kvt*16 + quad*4 + j, n = d = nt*16 + l16;
      // Vs row d stored with chunk-of-8 swizzle keyed on d&7 (= fsw).
      const int vcol = (((kvt * 2 + (quad >> 1)) ^ fsw) << 3) + (quad & 1) * 4;
      uint2 vr[4];
#pragma unroll
      for (int nt = 0; nt < 4; ++nt)
        vr[nt] = *(const uint2*)&Vst[(nt * 16 + l16) * 64 + vcol];

      half4 pfr[2];
#pragma unroll
      for (int qt = 0; qt < 2; ++qt) {
        float p0 = EXP2F(sacc[qt][kvt][0]);
        float p1 = EXP2F(sacc[qt][kvt][1]);
        float p2 = EXP2F(sacc[qt][kvt][2]);
        float p3 = EXP2F(sacc[qt][kvt][3]);
        uint2 w;
        w.x = pkh(p0, p1);
        w.y = pkh(p2, p3);
        pfr[qt] = __builtin_bit_cast(half4, w);
      }
#pragma unroll
      for (int qt = 0; qt < 2; ++qt)
        lacc[qt] = __builtin_amdgcn_mfma_f32_16x16x16f16(
            pfr[qt], vone, lacc[qt], 0, 0, 0);
#pragma unroll
      for (int nt = 0; nt < 4; ++nt) {
        half4 vfr = __builtin_bit_cast(half4, vr[nt]);
#pragma unroll
        for (int qt = 0; qt < 2; ++qt)
          oacc[qt][nt] = __builtin_amdgcn_mfma_f32_16x16x16f16(
              pfr[qt], vfr, oacc[qt][nt], 0, 0, 0);
      }
    }
    // no trailing barrier: next iteration's leading barrier covers reuse.
  }

  // epilogue: lane holds denom lacc[qt][r] for row q = qt*16+quad*4+r —
  // exactly the rows it writes. No cross-lane reduction needed.
  const int b = bh >> 4, h = bh & 15;
#pragma unroll
  for (int qt = 0; qt < 2; ++qt) {
    float inv0 = 1.f / lacc[qt][0], inv1 = 1.f / lacc[qt][1];
    float inv2 = 1.f / lacc[qt][2], inv3 = 1.f / lacc[qt][3];
#pragma unroll
    for (int nt = 0; nt < 4; ++nt) {
      int d = nt * 16 + l16;
      int qbase = q0 + wave * 32 + qt * 16 + quad * 4;
      size_t obase = ((size_t)(b * 2048 + qbase)) * 1024 + h * 64 + d;
      ob[obase]        = f2bf(oacc[qt][nt][0] * inv0);
      ob[obase + 1024] = f2bf(oacc[qt][nt][1] * inv1);
      ob[obase + 2048] = f2bf(oacc[qt][nt][2] * inv2);
      ob[obase + 3072] = f2bf(oacc[qt][nt][3] * inv3);
    }
  }
}

// ----------------------------- launch --------------------------------------

extern "C" void kernel_launch(void* const* d_in, const int* in_sizes, int n_in,
                              void* d_out, int out_size, void* d_ws, size_t ws_size,
                              hipStream_t stream) {
  const float* x      = (const float*)d_in[0];
  const float* w_qkv  = (const float*)d_in[1];
  const float* b_qkv  = (const float*)d_in[2];
  const float* w_proj = (const float*)d_in[3];
  const float* b_proj = (const float*)d_in[4];
  float* out = (float*)d_out;

  short* xs     = (short*)d_ws;                     // [8192,1024]
  short* wqkvT  = xs + (size_t)8192 * 1024;         // [3072,1024]
  short* wprojT = wqkvT + (size_t)3072 * 1024;      // [1024,1024]
  short* qb     = wprojT + (size_t)1024 * 1024;     // [64,2048,64]
  short* kb     = qb + (size_t)64 * 2048 * 64;      // [64,2048,64]
  short* vtb    = kb + (size_t)64 * 2048 * 64;      // [64,64,2048] f16
  short* aob    = vtb + (size_t)64 * 2048 * 64;     // [8192,1024]

  prep_kernel<<<dim3(8192), 256, 0, stream>>>(x, w_qkv, w_proj,
                                              xs, wqkvT, wprojT);

  gemm_kernel<256, 128, 0><<<dim3(24, 32), 256, 0, stream>>>(
      xs, wqkvT, b_qkv, 3072, qb, kb, vtb, nullptr);
  attn_kernel<<<dim3(16, 64), 256, 0, stream>>>(qb, kb, vtb, aob);
  gemm_kernel<128, 128, 1><<<dim3(8, 64), 256, 0, stream>>>(
      aob, wprojT, b_proj, 1024, nullptr, nullptr, nullptr, out);
}

// Round 7
// 263.416 us; speedup vs baseline: 1.1080x; 1.0140x over previous
//
#include <hip/hip_runtime.h>
#include <cstdint>
#include <cstddef>

// ---------------------------------------------------------------------------
// MSA: out = proj(softmax(Q K^T * scale) V) for B=4, N=2048, C=1024, H=16, HD=64
// bf16/f16 MFMA pipeline:
//   1. prep (ONE dispatch): x -> bf16; transpose-convert w_qkv, w_proj.
//   2. GEMM qkv: 256x128 tile, 4 waves x (128x64 out), BK=32, triple-buffered
//      LDS (2 blocks/CU), one raw barrier/K-tile, counted vmcnt.
//      XCD/L2-aware block remap.
//   3. attention: 128 q/block, 4 waves x 32 q-rows, BKV=64, S^T=K·Q^T,
//      no-max softmax, p=exp2(s); S^T C-layout == A-layout of
//      mfma_f32_16x16x16_f16 -> P feeds PV from registers.
//      R7: tile split into two 32-kv halves, software-pipelined so
//      exp2(A) overlaps QK^T(B) and exp2(B) overlaps PV(A) — R6 counters
//      showed MfmaUtil+VALUBusy ~= 97% (pipes serialized, wall = sum).
//      setprio(1) around PV MFMA clusters. Denominator via ones-B MFMA
//      (lane holds denom for exactly its output rows; no shfl/LDS reduce).
//      K+V LDS double-buffered, 1 barrier/tile, 4 blocks/CU, bijective XCD
//      swizzle (FETCH 142->28 MB measured).
//   4. GEMM proj: same kernel, 128x128 tile -> fp32 d_out
// ---------------------------------------------------------------------------

typedef __attribute__((ext_vector_type(8))) short short8;   // 8 x bf16 (4 VGPRs)
typedef __attribute__((ext_vector_type(4))) float f32x4;    // MFMA C/D
typedef _Float16 half4 __attribute__((ext_vector_type(4))); // 16x16x16 A/B frag

#if __has_builtin(__builtin_amdgcn_exp2f)
#define EXP2F(x) __builtin_amdgcn_exp2f(x)
#else
#define EXP2F(x) __expf((x) * 0.69314718056f)
#endif

__device__ __forceinline__ short f2bf(float x) {            // RNE float->bf16 bits
  unsigned u = __builtin_bit_cast(unsigned, x);
  u += 0x7fffu + ((u >> 16) & 1u);
  return (short)(u >> 16);
}

__device__ __forceinline__ unsigned pkh(float a, float b) { // pack 2xf32 -> f16x2
  auto h = __builtin_amdgcn_cvt_pkrtz(a, b);                // __fp16 ext_vector(2)
  return __builtin_bit_cast(unsigned, h);
}

__device__ __forceinline__ void async16(const void* g, void* l) {
  // 16B per lane, LDS dest = wave-uniform base + lane*16
  __builtin_amdgcn_global_load_lds(
      (const __attribute__((address_space(1))) unsigned*)g,
      (__attribute__((address_space(3))) unsigned*)l, 16, 0, 0);
}

__device__ __forceinline__ void barrier_raw() {
  __asm__ volatile("" ::: "memory");
  __builtin_amdgcn_s_barrier();
  __asm__ volatile("" ::: "memory");
}

// ------------------------------- prep --------------------------------------
// One dispatch: blocks [0,4096) convert x; [4096,7168) transpose w_qkv;
// [7168,8192) transpose w_proj. Branch is block-uniform; barriers legal.

__global__ __launch_bounds__(256) void prep_kernel(
    const float* __restrict__ x, const float* __restrict__ w_qkv,
    const float* __restrict__ w_proj, short* __restrict__ xs,
    short* __restrict__ wqkvT, short* __restrict__ wprojT) {
  __shared__ float tile[32][33];
  const int bid = blockIdx.x, tid = threadIdx.x;
  if (bid < 4096) {                                // x -> bf16, 8 elems/thread
    int i = bid * 256 + tid;
    const float4* p = (const float4*)x + (size_t)i * 2;
    float4 a = p[0], b = p[1];
    short8 r;
    r[0] = f2bf(a.x); r[1] = f2bf(a.y); r[2] = f2bf(a.z); r[3] = f2bf(a.w);
    r[4] = f2bf(b.x); r[5] = f2bf(b.y); r[6] = f2bf(b.z); r[7] = f2bf(b.w);
    *((short8*)xs + i) = r;
    return;
  }
  const float* in;
  short* out;
  int N, bx, by;
  if (bid < 4096 + 3072) {
    int b = bid - 4096;
    in = w_qkv; out = wqkvT; N = 3072; bx = b % 96; by = b / 96;
  } else {
    int b = bid - 7168;
    in = w_proj; out = wprojT; N = 1024; bx = b & 31; by = b >> 5;
  }
  const int K = 1024;
  int n0 = bx * 32, k0 = by * 32;
  int tx = tid & 31, ty = tid >> 5;                // (32,8)
  for (int r = ty; r < 32; r += 8)
    tile[r][tx] = in[(size_t)(k0 + r) * N + n0 + tx];
  __syncthreads();
  for (int r = ty; r < 32; r += 8)
    out[(size_t)(n0 + r) * K + k0 + tx] = f2bf(tile[tx][r]);
}

// ------------------------------- GEMM --------------------------------------
// C[M,Nn] = A[M,1024] * Bt[Nn,1024]^T ; BM x BN block tile, BK=32, 4 waves
// as 2Mx2N, each wave (BM/2)x(BN/2) out = (BM/32)x(BN/32) 16x16x32 MFMA/tile.
// LDS: one [BM+BN][32]-short tile per buffer, chunk-of-4 (16B) XOR swizzle
// applied at stage-source AND frag-read -> conflict-free b128 reads.
// TRIPLE buffered: while computing tile t, stage t+2; end-of-tile wait
// vmcnt(L) keeps t+2's L loads in flight. ONE raw s_barrier per K-tile.
// Block remap: XCD c (id%8) owns m-panels [c*MC,(c+1)*MC); n in chunks of 8.
// MODE 0: QKV epilogue (bias, scale Q by SCALE*log2e, scatter q/k bf16, vT f16)
// MODE 1: proj epilogue (bias, fp32 out)

template <int BM, int BN, int MODE>
__global__ __launch_bounds__(256, 2) void gemm_kernel(
    const short* __restrict__ A, const short* __restrict__ Bt,
    const float* __restrict__ bias, int Nn,
    short* __restrict__ qb, short* __restrict__ kb, short* __restrict__ vtb,
    float* __restrict__ outp) {
  constexpr int K = 1024;
  constexpr int NT = K / 32;                       // 32 K-tiles
  constexpr int MR = BM / 32, NR = BN / 32;        // frags per wave
  constexpr int L = (BM + BN) / 64;                // async16 per thread per tile
  __shared__ __align__(16) short Ts[3][(BM + BN) * 32];
  const int tid = threadIdx.x, wave = tid >> 6, lane = tid & 63;
  const int quad = lane >> 4, l16 = lane & 15;

  // XCD/L2-aware remap: id -> (c = id%8, j = id/8); XCD c owns MC m-panels;
  // within, n in chunks of 8 (requires gridDim.x*gridDim.y % 8 == 0).
  const unsigned bid = blockIdx.x + gridDim.x * blockIdx.y;
  const unsigned c = bid & 7u, j = bid >> 3;
  const unsigned MC = gridDim.y >> 3;              // m-panels per XCD
  const unsigned chunk = MC * 8u;                  // blocks per n-chunk per XCD
  const unsigned nc = j / chunk, rem = j - nc * chunk;
  const unsigned m_idx = c * MC + (rem >> 3);
  const unsigned n_idx = nc * 8u + (rem & 7u);
  const int m0 = (int)m_idx * BM, n0 = (int)n_idx * BN;

  const int wrow = (wave >> 1) * (BM / 2), wcol = (wave & 1) * (BN / 2);

  // staging: row = i*64 + (tid>>2), 16B chunk = tid&3, src chunk XOR (row&3)
  const int srow = tid >> 2;
  const int sch8 = (((tid & 3) ^ (srow & 3)) * 8);          // shorts
  const short* Ag = A + (size_t)(m0 + srow) * K + sch8;
  const short* Bg = Bt + (size_t)(n0 + srow) * K + sch8;
  const int fq8 = ((quad ^ (l16 & 3)) * 8);                 // frag chunk (shorts)

  f32x4 acc[MR][NR] = {};

  auto stage = [&](int b, int kt) {
    char* dst = (char*)Ts[b] + tid * 16;
#pragma unroll
    for (int i = 0; i < BM / 64; ++i)
      async16(Ag + (size_t)(i * 64) * K + kt * 32, dst + i * 4096);
#pragma unroll
    for (int i = 0; i < BN / 64; ++i)
      async16(Bg + (size_t)(i * 64) * K + kt * 32, dst + (BM / 64 + i) * 4096);
  };

  // prologue: stage tiles 0,1 into bufs 0,1; wait tile 0 (keep 1 in flight)
  stage(0, 0);
  stage(1, 1);
  if constexpr (L == 6) asm volatile("s_waitcnt vmcnt(6)" ::: "memory");
  else                  asm volatile("s_waitcnt vmcnt(4)" ::: "memory");
  barrier_raw();

  int cb = 0, sb = 2;
  for (int t = 0; t < NT; ++t) {
    if (t + 2 < NT) stage(sb, t + 2);

    const short* Tb = Ts[cb];
    short8 af[MR], bf[NR];
#pragma unroll
    for (int mf = 0; mf < MR; ++mf)
      af[mf] = *(const short8*)&Tb[(wrow + mf * 16 + l16) * 32 + fq8];
#pragma unroll
    for (int nf = 0; nf < NR; ++nf)
      bf[nf] = *(const short8*)&Tb[(BM + wcol + nf * 16 + l16) * 32 + fq8];

    __builtin_amdgcn_s_setprio(1);
#pragma unroll
    for (int mf = 0; mf < MR; ++mf)
#pragma unroll
      for (int nf = 0; nf < NR; ++nf)
        acc[mf][nf] = __builtin_amdgcn_mfma_f32_16x16x32_bf16(
            af[mf], bf[nf], acc[mf][nf], 0, 0, 0);
    __builtin_amdgcn_s_setprio(0);

    // counted wait: keep t+2's L loads in flight; t+1's (a tile old) retired.
    if (t + 2 < NT) {
      if constexpr (L == 6) asm volatile("s_waitcnt vmcnt(6)" ::: "memory");
      else                  asm volatile("s_waitcnt vmcnt(4)" ::: "memory");
    } else {
      asm volatile("s_waitcnt vmcnt(0)" ::: "memory");
    }
    barrier_raw();
    cb = cb + 1; if (cb >= 3) cb -= 3;
    sb = sb + 1; if (sb >= 3) sb -= 3;
  }

  // epilogue: C/D layout col = l16, row = quad*4 + reg
  if (MODE == 0) {
#pragma unroll
    for (int mf = 0; mf < MR; ++mf) {
      int row0 = m0 + wrow + mf * 16 + quad * 4;
      int b = row0 >> 11, n = row0 & 2047;
#pragma unroll
      for (int nf = 0; nf < NR; ++nf) {
        int col = n0 + wcol + nf * 16 + l16;
        float bv = bias[col];
        float v0 = acc[mf][nf][0] + bv, v1 = acc[mf][nf][1] + bv;
        float v2 = acc[mf][nf][2] + bv, v3 = acc[mf][nf][3] + bv;
        int which = col >> 10;
        int h = (col >> 6) & 15;
        int d = col & 63;
        size_t bh = (size_t)(b * 16 + h);
        if (which == 0) {             // Q, pre-scaled by SCALE*log2(e)
          const float qs = 0.18033688f;   // 0.125 * 1.44269504
          size_t base = (bh * 2048 + n) * 64 + d;
          qb[base]       = f2bf(v0 * qs);
          qb[base + 64]  = f2bf(v1 * qs);
          qb[base + 128] = f2bf(v2 * qs);
          qb[base + 192] = f2bf(v3 * qs);
        } else if (which == 1) {      // K
          size_t base = (bh * 2048 + n) * 64 + d;
          kb[base]       = f2bf(v0);
          kb[base + 64]  = f2bf(v1);
          kb[base + 128] = f2bf(v2);
          kb[base + 192] = f2bf(v3);
        } else {                      // V transposed: [bh, d, n] f16, 4 tokens
          uint2 pk;
          pk.x = pkh(v0, v1);
          pk.y = pkh(v2, v3);
          *(uint2*)&vtb[(bh * 64 + d) * 2048 + n] = pk;
        }
      }
    }
  } else {
#pragma unroll
    for (int mf = 0; mf < MR; ++mf) {
      int row0 = m0 + wrow + mf * 16 + quad * 4;
#pragma unroll
      for (int nf = 0; nf < NR; ++nf) {
        int col = n0 + wcol + nf * 16 + l16;
        float bv = bias[col];
        outp[(size_t)row0 * Nn + col]       = acc[mf][nf][0] + bv;
        outp[(size_t)(row0 + 1) * Nn + col] = acc[mf][nf][1] + bv;
        outp[(size_t)(row0 + 2) * Nn + col] = acc[mf][nf][2] + bv;
        outp[(size_t)(row0 + 3) * Nn + col] = acc[mf][nf][3] + bv;
      }
    }
  }
}

// ----------------------------- attention -----------------------------------
// One block = one (b,h) x 128 q-rows; 4 waves, 32 q-rows each. BKV = 64.
// Q pre-scaled by SCALE*log2e. qb/kb: [BH,2048,64] bf16; vtb: [BH,64,2048] f16.
// S^T = K Q^T via 16x16x32 bf16 (A=K m=kv, B=Q n=q): lane holds
// q=qt*16+l16, kv=kvt*16+quad*4+r — the A-layout of mfma_f32_16x16x16_f16
// (m=l16, k=quad*4+j). P: exp2 -> pkrtz -> PV MFMA from registers.
// R7 software pipeline per tile (two 32-kv halves A=kvt{0,1}, B=kvt{2,3}):
//   QK^T(A); QK^T(B); vrA; exp2/pack(A)  [VALU overlaps QK^T(B) pipe];
//   PV(A)+ones [setprio 1]; vrB; exp2/pack(B) [VALU overlaps PV(A) pipe];
//   PV(B)+ones [setprio 1].
// Denominator: lacc[qt] = mfma(pfr, ones) — lane holds denom for exactly
// the rows it writes (C row = quad*4+r); no cross-lane reduce.
// K+V double-buffered, barrier-first prefetch, 1 barrier/tile, 4 blocks/CU.
// Bijective XCD swizzle: XCD c covers bh in [8c,8c+8) -> K/V set 4MB = L2.
// ob: [B, 2048, 1024] bf16 attention output.

__global__ __launch_bounds__(256, 4) void attn_kernel(
    const short* __restrict__ qb, const short* __restrict__ kb,
    const short* __restrict__ vtb, short* __restrict__ ob) {
  __shared__ __align__(16) short Ks[2][64 * 64];  // bf16 [kv][d]
  __shared__ __align__(16) short Vs[2][64 * 64];  // f16  [d][kv]
  const int tid = threadIdx.x, wave = tid >> 6, lane = tid & 63;
  const int quad = lane >> 4, l16 = lane & 15;
  // XCD-bijective remap: linear id n -> n' = (n%8)*128 + n/8, so XCD c
  // (blocks n with n%8==c under round-robin dispatch) covers bh in [8c,8c+8).
  int nlin = blockIdx.x + blockIdx.y * 16;
  nlin = (nlin & 7) * 128 + (nlin >> 3);
  const int q0 = (nlin & 15) * 128;
  const int bh = nlin >> 4;
  const short* Qg = qb + (size_t)bh * (2048 * 64);
  const short* Kg = kb + (size_t)bh * (2048 * 64);
  const short* Vg = vtb + (size_t)bh * (64 * 2048);

  // Q fragments: global -> registers once; B-operand layout (n=q on l16,
  // k = kc*32 + quad*8 + j contiguous d)
  short8 qf[2][2];
#pragma unroll
  for (int qt = 0; qt < 2; ++qt)
#pragma unroll
    for (int kc = 0; kc < 2; ++kc)
      qf[qt][kc] = *(const short8*)
          &Qg[(size_t)(q0 + wave * 32 + qt * 16 + l16) * 64 + kc * 32 + quad * 8];

  const int str = lane >> 3;
  const int sgc = ((lane & 7) ^ (str & 7)) * 8;   // chunk-of-8 swizzle (shorts)
  const int fsw = l16 & 7;
  const int c0 = wave * 2, c1 = wave * 2 + 1;

  // prologue: stage K/V tile 0 into buffer 0
  async16(Kg + (size_t)(c0 * 8 + str) * 64 + sgc, (char*)Ks[0] + c0 * 1024);
  async16(Kg + (size_t)(c1 * 8 + str) * 64 + sgc, (char*)Ks[0] + c1 * 1024);
  async16(Vg + (size_t)(c0 * 8 + str) * 2048 + sgc, (char*)Vs[0] + c0 * 1024);
  async16(Vg + (size_t)(c1 * 8 + str) * 2048 + sgc, (char*)Vs[0] + c1 * 1024);

  const half4 vone = {(_Float16)1.f, (_Float16)1.f, (_Float16)1.f, (_Float16)1.f};
  const f32x4 fz = {};                           // hoisted zero C-operand
  f32x4 oacc[2][4] = {};   // [qt][nt]; C/D: col(n=d)=l16, row(m=q)=quad*4+r
  f32x4 lacc[2] = {};      // [qt]; denom for q = qt*16 + quad*4 + r

  for (int t = 0; t < 32; ++t) {
    // barrier FIRST: drains buf[t&1] loads (issued last iter / prologue,
    // overlapped with compute of t-1) and protects buffer reuse.
    __syncthreads();

    int kvn = (t + 1) * 64;
    if (kvn < 2048) {
      char* kd = (char*)Ks[(t + 1) & 1];
      char* vd = (char*)Vs[(t + 1) & 1];
      async16(Kg + (size_t)(kvn + c0 * 8 + str) * 64 + sgc, kd + c0 * 1024);
      async16(Kg + (size_t)(kvn + c1 * 8 + str) * 64 + sgc, kd + c1 * 1024);
      async16(Vg + (size_t)(c0 * 8 + str) * 2048 + kvn + sgc, vd + c0 * 1024);
      async16(Vg + (size_t)(c1 * 8 + str) * 2048 + kvn + sgc, vd + c1 * 1024);
    }
    const short* Kst = Ks[t & 1];
    const short* Vst = Vs[t & 1];

    // ---- QK^T half A (kvt 0,1) then half B (kvt 2,3): MFMA pipe fills ----
    f32x4 sA[2][2], sB[2][2];    // [qt][vv]
#pragma unroll
    for (int kc = 0; kc < 2; ++kc) {
      short8 k0 = *(const short8*)
          &Kst[(0 * 16 + l16) * 64 + (((kc * 4 + quad) ^ fsw) << 3)];
      short8 k1 = *(const short8*)
          &Kst[(1 * 16 + l16) * 64 + (((kc * 4 + quad) ^ fsw) << 3)];
#pragma unroll
      for (int qt = 0; qt < 2; ++qt) {
        sA[qt][0] = __builtin_amdgcn_mfma_f32_16x16x32_bf16(
            k0, qf[qt][kc], kc == 0 ? fz : sA[qt][0], 0, 0, 0);
        sA[qt][1] = __builtin_amdgcn_mfma_f32_16x16x32_bf16(
            k1, qf[qt][kc], kc == 0 ? fz : sA[qt][1], 0, 0, 0);
      }
    }
#pragma unroll
    for (int kc = 0; kc < 2; ++kc) {
      short8 k2 = *(const short8*)
          &Kst[(2 * 16 + l16) * 64 + (((kc * 4 + quad) ^ fsw) << 3)];
      short8 k3 = *(const short8*)
          &Kst[(3 * 16 + l16) * 64 + (((kc * 4 + quad) ^ fsw) << 3)];
#pragma unroll
      for (int qt = 0; qt < 2; ++qt) {
        sB[qt][0] = __builtin_amdgcn_mfma_f32_16x16x32_bf16(
            k2, qf[qt][kc], kc == 0 ? fz : sB[qt][0], 0, 0, 0);
        sB[qt][1] = __builtin_amdgcn_mfma_f32_16x16x32_bf16(
            k3, qf[qt][kc], kc == 0 ? fz : sB[qt][1], 0, 0, 0);
      }
    }

    // ---- half A: V reads, exp2/pack (VALU overlaps QK^T(B) pipe) ----
    uint2 vrA[2][4];             // [vv][nt]
#pragma unroll
    for (int vv = 0; vv < 2; ++vv) {
      const int kvt = vv;
      const int vcol = (((kvt * 2 + (quad >> 1)) ^ fsw) << 3) + (quad & 1) * 4;
#pragma unroll
      for (int nt = 0; nt < 4; ++nt)
        vrA[vv][nt] = *(const uint2*)&Vst[(nt * 16 + l16) * 64 + vcol];
    }
    half4 pfA[2][2];             // [qt][vv]
#pragma unroll
    for (int qt = 0; qt < 2; ++qt)
#pragma unroll
      for (int vv = 0; vv < 2; ++vv) {
        float p0 = EXP2F(sA[qt][vv][0]);
        float p1 = EXP2F(sA[qt][vv][1]);
        float p2 = EXP2F(sA[qt][vv][2]);
        float p3 = EXP2F(sA[qt][vv][3]);
        uint2 w;
        w.x = pkh(p0, p1);
        w.y = pkh(p2, p3);
        pfA[qt][vv] = __builtin_bit_cast(half4, w);
      }

    // ---- PV(A) + ones(A) ----
    __builtin_amdgcn_s_setprio(1);
#pragma unroll
    for (int vv = 0; vv < 2; ++vv) {
#pragma unroll
      for (int qt = 0; qt < 2; ++qt)
        lacc[qt] = __builtin_amdgcn_mfma_f32_16x16x16f16(
            pfA[qt][vv], vone, lacc[qt], 0, 0, 0);
#pragma unroll
      for (int nt = 0; nt < 4; ++nt) {
        half4 vfr = __builtin_bit_cast(half4, vrA[vv][nt]);
#pragma unroll
        for (int qt = 0; qt < 2; ++qt)
          oacc[qt][nt] = __builtin_amdgcn_mfma_f32_16x16x16f16(
              pfA[qt][vv], vfr, oacc[qt][nt], 0, 0, 0);
      }
    }
    __builtin_amdgcn_s_setprio(0);

    // ---- half B: V reads, exp2/pack (VALU overlaps PV(A) pipe) ----
    uint2 vrB[2][4];
#pragma unroll
    for (int vv = 0; vv < 2; ++vv) {
      const int kvt = 2 + vv;
      const int vcol = (((kvt * 2 + (quad >> 1)) ^ fsw) << 3) + (quad & 1) * 4;
#pragma unroll
      for (int nt = 0; nt < 4; ++nt)
        vrB[vv][nt] = *(const uint2*)&Vst[(nt * 16 + l16) * 64 + vcol];
    }
    half4 pfB[2][2];
#pragma unroll
    for (int qt = 0; qt < 2; ++qt)
#pragma unroll
      for (int vv = 0; vv < 2; ++vv) {
        float p0 = EXP2F(sB[qt][vv][0]);
        float p1 = EXP2F(sB[qt][vv][1]);
        float p2 = EXP2F(sB[qt][vv][2]);
        float p3 = EXP2F(sB[qt][vv][3]);
        uint2 w;
        w.x = pkh(p0, p1);
        w.y = pkh(p2, p3);
        pfB[qt][vv] = __builtin_bit_cast(half4, w);
      }

    // ---- PV(B) + ones(B) ----
    __builtin_amdgcn_s_setprio(1);
#pragma unroll
    for (int vv = 0; vv < 2; ++vv) {
#pragma unroll
      for (int qt = 0; qt < 2; ++qt)
        lacc[qt] = __builtin_amdgcn_mfma_f32_16x16x16f16(
            pfB[qt][vv], vone, lacc[qt], 0, 0, 0);
#pragma unroll
      for (int nt = 0; nt < 4; ++nt) {
        half4 vfr = __builtin_bit_cast(half4, vrB[vv][nt]);
#pragma unroll
        for (int qt = 0; qt < 2; ++qt)
          oacc[qt][nt] = __builtin_amdgcn_mfma_f32_16x16x16f16(
              pfB[qt][vv], vfr, oacc[qt][nt], 0, 0, 0);
      }
    }
    __builtin_amdgcn_s_setprio(0);
    // no trailing barrier: next iteration's leading barrier covers reuse.
  }

  // epilogue: lane holds denom lacc[qt][r] for row q = qt*16+quad*4+r —
  // exactly the rows it writes. No cross-lane reduction needed.
  const int b = bh >> 4, h = bh & 15;
#pragma unroll
  for (int qt = 0; qt < 2; ++qt) {
    float inv0 = 1.f / lacc[qt][0], inv1 = 1.f / lacc[qt][1];
    float inv2 = 1.f / lacc[qt][2], inv3 = 1.f / lacc[qt][3];
#pragma unroll
    for (int nt = 0; nt < 4; ++nt) {
      int d = nt * 16 + l16;
      int qbase = q0 + wave * 32 + qt * 16 + quad * 4;
      size_t obase = ((size_t)(b * 2048 + qbase)) * 1024 + h * 64 + d;
      ob[obase]        = f2bf(oacc[qt][nt][0] * inv0);
      ob[obase + 1024] = f2bf(oacc[qt][nt][1] * inv1);
      ob[obase + 2048] = f2bf(oacc[qt][nt][2] * inv2);
      ob[obase + 3072] = f2bf(oacc[qt][nt][3] * inv3);
    }
  }
}

// ----------------------------- launch --------------------------------------

extern "C" void kernel_launch(void* const* d_in, const int* in_sizes, int n_in,
                              void* d_out, int out_size, void* d_ws, size_t ws_size,
                              hipStream_t stream) {
  const float* x      = (const float*)d_in[0];
  const float* w_qkv  = (const float*)d_in[1];
  const float* b_qkv  = (const float*)d_in[2];
  const float* w_proj = (const float*)d_in[3];
  const float* b_proj = (const float*)d_in[4];
  float* out = (float*)d_out;

  short* xs     = (short*)d_ws;                     // [8192,1024]
  short* wqkvT  = xs + (size_t)8192 * 1024;         // [3072,1024]
  short* wprojT = wqkvT + (size_t)3072 * 1024;      // [1024,1024]
  short* qb     = wprojT + (size_t)1024 * 1024;     // [64,2048,64]
  short* kb     = qb + (size_t)64 * 2048 * 64;      // [64,2048,64]
  short* vtb    = kb + (size_t)64 * 2048 * 64;      // [64,64,2048] f16
  short* aob    = vtb + (size_t)64 * 2048 * 64;     // [8192,1024]

  prep_kernel<<<dim3(8192), 256, 0, stream>>>(x, w_qkv, w_proj,
                                              xs, wqkvT, wprojT);

  gemm_kernel<256, 128, 0><<<dim3(24, 32), 256, 0, stream>>>(
      xs, wqkvT, b_qkv, 3072, qb, kb, vtb, nullptr);
  attn_kernel<<<dim3(16, 64), 256, 0, stream>>>(qb, kb, vtb, aob);
  gemm_kernel<128, 128, 1><<<dim3(8, 64), 256, 0, stream>>>(
      aob, wprojT, b_proj, 1024, nullptr, nullptr, nullptr, out);
}